// Round 4
// baseline (94.626 us; speedup 1.0000x reference)
//
#include <hip/hip_runtime.h>
#include <hip/hip_bf16.h>

// GMM log-likelihood, N=65536, K=32, F=128.
// Hybrid split: wave (gh,nh) owns g-half gh (64 rows of P^T, 2 gt-tiles) and
// n-half nh (64 x-rows, 2 n-tiles). 16 ds_read_b128 -> 32 MFMAs per comp per
// wave. Even/odd accumulator banks: epilogue of comp k-1 (squares + pairwise
// LDS exchange + per-lane LSE) overlaps the MFMAs of comp k. One barrier/comp.

#define NPTS 65536
#define KC 32
#define FD 128
#define SLABB 32768  // 4 q * 8 s * 64 lanes * 16 B per component

typedef __attribute__((ext_vector_type(8))) short short8;
typedef __attribute__((ext_vector_type(8))) unsigned short ushort8;
typedef __attribute__((ext_vector_type(16))) float f32x16;

static __device__ __forceinline__ unsigned short f2bf(float f) {
  unsigned int u = __float_as_uint(f);
  u += 0x7FFFu + ((u >> 16) & 1u);  // RNE
  return (unsigned short)(u >> 16);
}

// --- prep 1: mp2 = NEGATED permuted mu@P projections + ck2 ---
// mp2[((k*4+gt)*2+half)*16 + i] = -sum_f means[k][f]*P[k][f][g],
//   g = gt*32 + 4*half + (i&3) + 8*(i>>2)   (32x32 MFMA C-row layout)
__global__ void prep_mproj(const float* __restrict__ means, const float* __restrict__ P,
                           const float* __restrict__ w, float* __restrict__ mp2,
                           float* __restrict__ ck2) {
  int k = blockIdx.x, g = threadIdx.x;  // 32 x 128
  const float* Pk = P + k * FD * FD;
  float acc = 0.f;
  for (int f = 0; f < FD; ++f) acc = fmaf(means[k * FD + f], Pk[f * FD + g], acc);
  int gt = g >> 5, r = g & 31;
  int half = (r >> 2) & 1;
  int i = (r & 3) | ((r >> 3) << 2);
  mp2[((k * 4 + gt) * 2 + half) * 16 + i] = -acc;
  __shared__ float red[FD];
  red[g] = logf(Pk[g * FD + g]);
  __syncthreads();
  for (int off = 64; off; off >>= 1) {
    if (g < off) red[g] += red[g + off];
    __syncthreads();
  }
  if (g == 0) ck2[k] = logf(w[k]) + red[0] - 0.5f * (float)FD * 1.8378770664093453f;
}

// --- prep 2: frag-major bf16 A image. chunk id -> (k,q,s,lane).
// lane l supplies row g=q*32+(l&31), elements f = 16s + 8*(l>>5) + j.
__global__ void prep_A(const float* __restrict__ P, unsigned char* __restrict__ Aimg) {
  int id = blockIdx.x * 256 + threadIdx.x;  // 0..65535
  int l = id & 63;
  int s = (id >> 6) & 7;
  int q = (id >> 9) & 3;
  int k = id >> 11;
  int g = q * 32 + (l & 31);
  int f0 = 16 * s + 8 * (l >> 5);
  ushort8 v;
#pragma unroll
  for (int j = 0; j < 8; ++j) v[j] = f2bf(P[k * 16384 + (f0 + j) * 128 + g]);
  *(ushort8*)(Aimg + (size_t)id * 16) = v;
}

// --- main body: MFMAs of comp k into `cur`, epilogue of comp k-1 from `prev` ---
template <int RB, int WB, int PH, bool FIRST, bool LASTK>
__device__ __forceinline__ void comp_body(
    int k, const unsigned char* __restrict__ Aimg, const float* __restrict__ mp2,
    unsigned char* abuf, float (&xch)[2][2][2][64], const float* ck, int wid, int gh,
    int nh, int lane, int half, const short8 (&xf)[2][8], const float4 (&mpc)[8],
    float4 (&mpn)[8], f32x16 (&cur)[2][2], f32x16 (&prev)[2][2], float& m,
    float& ssum) {
  if (!LASTK) {
    // stage A(k+1) into the other buffer (own quarter, linear both sides)
    const unsigned char* gs = Aimg + (size_t)(k + 1) * SLABB + wid * 8192 + lane * 16;
    unsigned char* ls = abuf + WB + wid * 8192;
#pragma unroll
    for (int i = 0; i < 8; ++i)
      __builtin_amdgcn_global_load_lds(
          (const __attribute__((address_space(1))) void*)(gs + i * 1024),
          (__attribute__((address_space(3))) void*)(ls + i * 1024), 16, 0, 0);
    __builtin_amdgcn_sched_barrier(0);  // keep stage loads ahead of mp loads
    // prefetch mp(k+1) into registers
#pragma unroll
    for (int g2 = 0; g2 < 2; ++g2) {
      const float4* mpp =
          (const float4*)(mp2 + ((size_t)((k + 1) * 4 + gh * 2 + g2) * 2 + half) * 16);
#pragma unroll
      for (int w = 0; w < 4; ++w) mpn[g2 * 4 + w] = mpp[w];
    }
  }
  // MFMA phase: C-init from mp(k) regs (already negated), A from LDS, B from regs
#pragma unroll
  for (int g2 = 0; g2 < 2; ++g2) {
    f32x16 c0, c1;
#pragma unroll
    for (int i = 0; i < 16; ++i) {
      float v = ((const float*)&mpc[g2 * 4 + (i >> 2)])[i & 3];
      c0[i] = v;
      c1[i] = v;
    }
#pragma unroll
    for (int s = 0; s < 8; ++s) {
      const short8 a =
          *(const short8*)(abuf + RB + ((gh * 2 + g2) * 8 + s) * 1024 + lane * 16);
      c0 = __builtin_amdgcn_mfma_f32_32x32x16_bf16(a, xf[0][s], c0, 0, 0, 0);
      c1 = __builtin_amdgcn_mfma_f32_32x32x16_bf16(a, xf[1][s], c1, 0, 0, 0);
    }
    cur[g2][0] = c0;
    cur[g2][1] = c1;
  }
  // epilogue of comp k-1 (register-only; overlaps in-flight MFMAs of comp k)
  float p0 = 0.f, p1 = 0.f;
  if (!FIRST) {
#pragma unroll
    for (int g2 = 0; g2 < 2; ++g2)
#pragma unroll
      for (int i = 0; i < 16; ++i) {
        p0 = fmaf(prev[g2][0][i], prev[g2][0][i], p0);
        p1 = fmaf(prev[g2][1][i], prev[g2][1][i], p1);
      }
    p0 += __shfl_xor(p0, 32, 64);  // add other 16 g-rows of each gt
    p1 += __shfl_xor(p1, 32, 64);
    xch[PH][gh][nh][lane] = half ? p1 : p0;  // partial over this wave's 64 g's
  }
  __syncthreads();  // xch visibility + A-staging coordination (one barrier/comp)
  if (!FIRST) {
    float tot = (half ? p1 : p0) + xch[PH][gh ^ 1][nh][lane];  // full 128-g sum
    float v = ck[k - 1] - 0.5f * tot;
    float nm = fmaxf(m, v);
    ssum = ssum * __expf(m - nm) + __expf(v - nm);
    m = nm;
  }
}

__global__ __launch_bounds__(256, 2) void gmm_main(const float* __restrict__ x,
                                                   const unsigned char* __restrict__ Aimg,
                                                   const float* __restrict__ mp2,
                                                   const float* __restrict__ ck2,
                                                   float* __restrict__ out) {
  __shared__ __align__(16) unsigned char abuf[2 * SLABB];
  __shared__ __align__(16) float xch[2][2][2][64];
  __shared__ float ck[KC];
  const int tid = threadIdx.x;
  const int wid = tid >> 6;
  const int lane = tid & 63;
  const int half = lane >> 5;
  const int ln = lane & 31;
  const int gh = wid & 1;   // g-half this wave owns (2 gt-tiles)
  const int nh = wid >> 1;  // n-half this wave owns (64 rows)
  const int nbase = blockIdx.x * 128;

  if (tid < KC) ck[tid] = ck2[tid];

  // stage comp 0 -> buf0 (quarter wid)
  {
    const unsigned char* gs = Aimg + wid * 8192 + lane * 16;
    unsigned char* ls = abuf + wid * 8192;
#pragma unroll
    for (int i = 0; i < 8; ++i)
      __builtin_amdgcn_global_load_lds(
          (const __attribute__((address_space(1))) void*)(gs + i * 1024),
          (__attribute__((address_space(3))) void*)(ls + i * 1024), 16, 0, 0);
  }
  // mp(0)
  float4 mpA[8], mpB[8];
#pragma unroll
  for (int g2 = 0; g2 < 2; ++g2) {
    const float4* mpp = (const float4*)(mp2 + ((size_t)(gh * 2 + g2) * 2 + half) * 16);
#pragma unroll
    for (int w = 0; w < 4; ++w) mpA[g2 * 4 + w] = mpp[w];
  }

  // B fragments: this wave's 64 x-rows (2 n-tiles) resident in registers.
  // xf[t][s][j] = x[nbase + nh*64 + t*32 + ln][16s + 8*half + j]
  short8 xf[2][8];
#pragma unroll
  for (int t = 0; t < 2; ++t) {
    const float* xr = x + (size_t)(nbase + nh * 64 + t * 32 + ln) * FD + 8 * half;
#pragma unroll
    for (int s = 0; s < 8; ++s) {
      const float4 a = *(const float4*)(xr + 16 * s);
      const float4 b = *(const float4*)(xr + 16 * s + 4);
      short8 f;
      f[0] = (short)f2bf(a.x); f[1] = (short)f2bf(a.y);
      f[2] = (short)f2bf(a.z); f[3] = (short)f2bf(a.w);
      f[4] = (short)f2bf(b.x); f[5] = (short)f2bf(b.y);
      f[6] = (short)f2bf(b.z); f[7] = (short)f2bf(b.w);
      xf[t][s] = f;
    }
  }

  asm volatile("s_waitcnt vmcnt(0)" ::: "memory");
  __syncthreads();

  f32x16 dA[2][2], dB[2][2];
  float m = -__builtin_inff(), ssum = 0.f;

  comp_body<0, SLABB, 1, true, false>(0, Aimg, mp2, abuf, xch, ck, wid, gh, nh, lane,
                                      half, xf, mpA, mpB, dA, dB, m, ssum);
  comp_body<SLABB, 0, 0, false, false>(1, Aimg, mp2, abuf, xch, ck, wid, gh, nh, lane,
                                       half, xf, mpB, mpA, dB, dA, m, ssum);
  for (int kk = 2; kk < KC - 2; kk += 2) {
    comp_body<0, SLABB, 1, false, false>(kk, Aimg, mp2, abuf, xch, ck, wid, gh, nh,
                                         lane, half, xf, mpA, mpB, dA, dB, m, ssum);
    comp_body<SLABB, 0, 0, false, false>(kk + 1, Aimg, mp2, abuf, xch, ck, wid, gh, nh,
                                         lane, half, xf, mpB, mpA, dB, dA, m, ssum);
  }
  comp_body<0, SLABB, 1, false, false>(KC - 2, Aimg, mp2, abuf, xch, ck, wid, gh, nh,
                                       lane, half, xf, mpA, mpB, dA, dB, m, ssum);
  comp_body<SLABB, 0, 0, false, true>(KC - 1, Aimg, mp2, abuf, xch, ck, wid, gh, nh,
                                      lane, half, xf, mpB, mpA, dB, dA, m, ssum);

  // tail epilogue for comp 31 (bank dB), ph = 1
  {
    float p0 = 0.f, p1 = 0.f;
#pragma unroll
    for (int g2 = 0; g2 < 2; ++g2)
#pragma unroll
      for (int i = 0; i < 16; ++i) {
        p0 = fmaf(dB[g2][0][i], dB[g2][0][i], p0);
        p1 = fmaf(dB[g2][1][i], dB[g2][1][i], p1);
      }
    p0 += __shfl_xor(p0, 32, 64);
    p1 += __shfl_xor(p1, 32, 64);
    xch[1][gh][nh][lane] = half ? p1 : p0;
    __syncthreads();
    float tot = (half ? p1 : p0) + xch[1][gh ^ 1][nh][lane];
    float v = ck[KC - 1] - 0.5f * tot;
    float nm = fmaxf(m, v);
    ssum = ssum * __expf(m - nm) + __expf(v - nm);
    m = nm;
  }

  if (gh == 0) out[nbase + nh * 64 + lane] = m + logf(ssum);
}

extern "C" void kernel_launch(void* const* d_in, const int* in_sizes, int n_in,
                              void* d_out, int out_size, void* d_ws, size_t ws_size,
                              hipStream_t stream) {
  const float* x = (const float*)d_in[0];
  const float* means = (const float*)d_in[1];
  const float* P = (const float*)d_in[2];
  const float* w = (const float*)d_in[3];
  float* out = (float*)d_out;

  unsigned char* ws = (unsigned char*)d_ws;
  unsigned char* Aimg = ws;                      // 32 * 32768 = 1048576 B
  float* mp2 = (float*)(ws + 1048576);           // 16384 B
  float* ck2 = (float*)(ws + 1048576 + 16384);   // 128 B

  prep_mproj<<<32, 128, 0, stream>>>(means, P, w, mp2, ck2);
  prep_A<<<256, 256, 0, stream>>>(P, Aimg);
  gmm_main<<<NPTS / 128, 256, 0, stream>>>(x, Aimg, mp2, ck2, out);
}

// Round 5
// 80.587 us; speedup vs baseline: 1.1742x; 1.1742x over previous
//
#include <hip/hip_runtime.h>
#include <hip/hip_bf16.h>

// GMM log-likelihood, N=65536, K=32, F=128.
// Wave owns 32 n-rows x all 128 g. Per comp: 32 ds_read_b128 + 32 MFMA,
// software-pipelined (frags read one 8-frag phase ahead, 2 register banks).
// Mean fold via v-trick: logprob = sum y^2 - 2*x.v_k + sum mp^2, with
// xv[n,k] computed once by an 8-MFMA prologue mini-GEMM and applied per comp
// at a compile-time register index (full template unroll of the 32 comps).
// One barrier per comp; stage loads span the whole body (vmcnt(0) is ~free).

#define NPTS 65536
#define KC 32
#define FD 128
#define SLABB 32768  // 4 q * 8 s * 64 lanes * 16 B per component

typedef __attribute__((ext_vector_type(8))) short short8;
typedef __attribute__((ext_vector_type(8))) unsigned short ushort8;
typedef __attribute__((ext_vector_type(16))) float f32x16;

static __device__ __forceinline__ unsigned short f2bf(float f) {
  unsigned int u = __float_as_uint(f);
  u += 0x7FFFu + ((u >> 16) & 1u);  // RNE
  return (unsigned short)(u >> 16);
}

// --- prep1: mp[k][g] = sum_f means[k][f]*P[k][f][g];
//     ck3[k] = log w + logdet - 0.5*(F*log2pi + sum_g mp^2) ---
__global__ void prep1(const float* __restrict__ means, const float* __restrict__ P,
                      const float* __restrict__ w, float* __restrict__ mp,
                      float* __restrict__ ck3) {
  int k = blockIdx.x, g = threadIdx.x;  // 32 x 128
  const float* Pk = P + k * FD * FD;
  float acc = 0.f;
  for (int f = 0; f < FD; ++f) acc = fmaf(means[k * FD + f], Pk[f * FD + g], acc);
  mp[k * FD + g] = acc;
  __shared__ float r1[FD], r2[FD];
  r1[g] = logf(Pk[g * FD + g]);
  r2[g] = acc * acc;
  __syncthreads();
  for (int off = 64; off; off >>= 1) {
    if (g < off) { r1[g] += r1[g + off]; r2[g] += r2[g + off]; }
    __syncthreads();
  }
  if (g == 0)
    ck3[k] = logf(w[k]) + r1[0] - 0.5f * ((float)FD * 1.8378770664093453f + r2[0]);
}

// --- prep2: v[k][f] = sum_g P[k][f][g] * mp[k][g]  (rows of P are contiguous) ---
__global__ void prep2(const float* __restrict__ P, const float* __restrict__ mp,
                      float* __restrict__ v) {
  int k = blockIdx.x, f = threadIdx.x;  // 32 x 128
  __shared__ float smp[FD];
  smp[f] = mp[k * FD + f];
  __syncthreads();
  const float* Pr = P + k * FD * FD + f * FD;
  float acc = 0.f;
  for (int g = 0; g < FD; ++g) acc = fmaf(Pr[g], smp[g], acc);
  v[k * FD + f] = acc;
}

// --- prep3: xv mini-slab (8 KB): A'[row k][f] = v[k][f], frag-major ---
__global__ void prep3(const float* __restrict__ v, unsigned char* __restrict__ Ximg) {
  int id = blockIdx.x * 256 + threadIdx.x;  // 0..511 chunks
  int l = id & 63, s = id >> 6;
  int r = l & 31, f0 = 16 * s + 8 * (l >> 5);
  ushort8 o;
#pragma unroll
  for (int j = 0; j < 8; ++j) o[j] = f2bf(v[r * FD + f0 + j]);
  *(ushort8*)(Ximg + (size_t)id * 16) = o;
}

// --- prep4: frag-major bf16 A image. chunk id -> (k,q,s,lane). ---
__global__ void prep4(const float* __restrict__ P, unsigned char* __restrict__ Aimg) {
  int id = blockIdx.x * 256 + threadIdx.x;  // 0..65535
  int l = id & 63;
  int s = (id >> 6) & 7;
  int q = (id >> 9) & 3;
  int k = id >> 11;
  int g = q * 32 + (l & 31);
  int f0 = 16 * s + 8 * (l >> 5);
  ushort8 o;
#pragma unroll
  for (int j = 0; j < 8; ++j) o[j] = f2bf(P[k * 16384 + (f0 + j) * 128 + g]);
  *(ushort8*)(Aimg + (size_t)id * 16) = o;
}

// --- main ---
__device__ __forceinline__ void rd8(short8 (&f)[8], const unsigned char* b) {
#pragma unroll
  for (int s = 0; s < 8; ++s) f[s] = *(const short8*)(b + s * 1024);
}
__device__ __forceinline__ void mm8(f32x16& a, const short8 (&f)[8], const short8 (&x)[8]) {
#pragma unroll
  for (int s = 0; s < 8; ++s)
    a = __builtin_amdgcn_mfma_f32_32x32x16_bf16(f[s], x[s], a, 0, 0, 0);
}

template <int K>
__device__ __forceinline__ void epi(const f32x16& p0, const f32x16& p1, const f32x16& p2,
                                    const f32x16& p3, const f32x16& xv, const float* ck,
                                    int half, float& m, float& ssum) {
  float s0 = 0.f, s1 = 0.f, s2 = 0.f, s3 = 0.f;
#pragma unroll
  for (int i = 0; i < 16; ++i) {
    s0 = fmaf(p0[i], p0[i], s0);
    s1 = fmaf(p1[i], p1[i], s1);
    s2 = fmaf(p2[i], p2[i], s2);
    s3 = fmaf(p3[i], p3[i], s3);
  }
  float s = (s0 + s1) + (s2 + s3);  // this lane's 64 g-rows
  constexpr int owner = (K >> 2) & 1;         // half that holds row k=K
  constexpr int idx = (K & 3) | ((K >> 3) << 2);
  if (half == owner) s = fmaf(-2.f, xv[idx], s);  // -2*x.v_k, added once
  s += __shfl_xor(s, 32, 64);  // + other half's 64 g-rows (and the xv term)
  float vv = ck[K] - 0.5f * s;
  float nm = fmaxf(m, vv);
  ssum = ssum * __expf(m - nm) + __expf(vv - nm);
  m = nm;
}

template <int K>
__device__ __forceinline__ void comp_iter(const unsigned char* __restrict__ Aimg,
                                          unsigned char* abuf, const float* ck, int wid,
                                          int lane, int half, const short8 (&xf)[8],
                                          const f32x16& xv, f32x16 p0, f32x16 p1,
                                          f32x16 p2, f32x16 p3, float& m, float& ssum) {
  constexpr int RB = (K & 1) * SLABB;
  constexpr int WB = SLABB - RB;
  if constexpr (K + 1 < KC) {
    // stage slab K+1 into the other buffer (readers of it finished last comp)
    const unsigned char* gs = Aimg + (size_t)(K + 1) * SLABB + wid * 8192 + lane * 16;
    unsigned char* ls = abuf + WB + wid * 8192;
#pragma unroll
    for (int i = 0; i < 8; ++i)
      __builtin_amdgcn_global_load_lds(
          (const __attribute__((address_space(1))) void*)(gs + i * 1024),
          (__attribute__((address_space(3))) void*)(ls + i * 1024), 16, 0, 0);
  }
  const unsigned char* rb = abuf + RB + lane * 16;
  short8 fA[8], fB[8];
  rd8(fA, rb);         // phase 0 (g-tile 0)
  rd8(fB, rb + 8192);  // phase 1
  // epilogue of comp K-1: VALU work hides the post-barrier ds_read latency
  if constexpr (K > 0) epi<K - 1>(p0, p1, p2, p3, xv, ck, half, m, ssum);
  f32x16 a0, a1, a2, a3;
#pragma unroll
  for (int i = 0; i < 16; ++i) { a0[i] = 0.f; a1[i] = 0.f; a2[i] = 0.f; a3[i] = 0.f; }
  __builtin_amdgcn_s_setprio(1);
  mm8(a0, fA, xf);
  rd8(fA, rb + 2 * 8192);  // phase 2 (overlaps phase-1 MFMAs)
  mm8(a1, fB, xf);
  rd8(fB, rb + 3 * 8192);  // phase 3
  mm8(a2, fA, xf);
  mm8(a3, fB, xf);
  __builtin_amdgcn_s_setprio(0);
  if constexpr (K + 1 < KC) {
    asm volatile("s_waitcnt vmcnt(0)" ::: "memory");  // stage K+1 landed (~free: spanned body)
    __syncthreads();
    comp_iter<K + 1>(Aimg, abuf, ck, wid, lane, half, xf, xv, a0, a1, a2, a3, m, ssum);
  } else {
    epi<K>(a0, a1, a2, a3, xv, ck, half, m, ssum);
  }
}

__global__ __launch_bounds__(256, 2) void gmm_main(const float* __restrict__ x,
                                                   const unsigned char* __restrict__ Aimg,
                                                   const unsigned char* __restrict__ Ximg,
                                                   const float* __restrict__ ck3,
                                                   float* __restrict__ out) {
  __shared__ __align__(16) unsigned char abuf[2 * SLABB];
  __shared__ float ck[KC];
  const int tid = threadIdx.x;
  const int wid = tid >> 6;
  const int lane = tid & 63;
  const int half = lane >> 5;
  const int ln = lane & 31;
  const int nbase = blockIdx.x * 128;

  if (tid < KC) ck[tid] = ck3[tid];

  // issue all prologue stages first: xv mini-slab -> buf1[0:8K], slab0 -> buf0
  {
    const unsigned char* gx = Ximg + wid * 2048 + lane * 16;
    unsigned char* lx = abuf + SLABB + wid * 2048;
    __builtin_amdgcn_global_load_lds((const __attribute__((address_space(1))) void*)gx,
                                     (__attribute__((address_space(3))) void*)lx, 16, 0, 0);
    __builtin_amdgcn_global_load_lds(
        (const __attribute__((address_space(1))) void*)(gx + 1024),
        (__attribute__((address_space(3))) void*)(lx + 1024), 16, 0, 0);
    const unsigned char* gs = Aimg + wid * 8192 + lane * 16;
    unsigned char* ls = abuf + wid * 8192;
#pragma unroll
    for (int i = 0; i < 8; ++i)
      __builtin_amdgcn_global_load_lds(
          (const __attribute__((address_space(1))) void*)(gs + i * 1024),
          (__attribute__((address_space(3))) void*)(ls + i * 1024), 16, 0, 0);
  }

  // B fragments: this wave's 32 x-rows, resident all kernel.
  // xf[s][j] = x[nbase + wid*32 + ln][16s + 8*half + j]
  short8 xf[8];
  {
    const float* xr = x + (size_t)(nbase + wid * 32 + ln) * FD + 8 * half;
#pragma unroll
    for (int s = 0; s < 8; ++s) {
      const float4 a = *(const float4*)(xr + 16 * s);
      const float4 b = *(const float4*)(xr + 16 * s + 4);
      short8 f;
      f[0] = (short)f2bf(a.x); f[1] = (short)f2bf(a.y);
      f[2] = (short)f2bf(a.z); f[3] = (short)f2bf(a.w);
      f[4] = (short)f2bf(b.x); f[5] = (short)f2bf(b.y);
      f[6] = (short)f2bf(b.z); f[7] = (short)f2bf(b.w);
      xf[s] = f;
    }
  }

  asm volatile("s_waitcnt vmcnt(0)" ::: "memory");
  __syncthreads();

  // xv[n, k] mini-GEMM: 8 MFMAs; row k = (i&3)+8*(i>>2)+4*half, col n = ln
  f32x16 xv;
#pragma unroll
  for (int i = 0; i < 16; ++i) xv[i] = 0.f;
  {
    short8 fx[8];
    rd8(fx, abuf + SLABB + lane * 16);
    mm8(xv, fx, xf);
  }
  asm volatile("s_waitcnt vmcnt(0) lgkmcnt(0)" ::: "memory");
  __syncthreads();  // all waves done with buf1's xv region; slab0 resident

  float m = -__builtin_inff(), ssum = 0.f;
  f32x16 z;
#pragma unroll
  for (int i = 0; i < 16; ++i) z[i] = 0.f;
  comp_iter<0>(Aimg, abuf, ck, wid, lane, half, xf, xv, z, z, z, z, m, ssum);

  if (half == 0) out[nbase + wid * 32 + ln] = m + logf(ssum);
}

extern "C" void kernel_launch(void* const* d_in, const int* in_sizes, int n_in,
                              void* d_out, int out_size, void* d_ws, size_t ws_size,
                              hipStream_t stream) {
  const float* x = (const float*)d_in[0];
  const float* means = (const float*)d_in[1];
  const float* P = (const float*)d_in[2];
  const float* w = (const float*)d_in[3];
  float* out = (float*)d_out;

  unsigned char* ws = (unsigned char*)d_ws;
  unsigned char* Aimg = ws;                       // 1048576 B
  unsigned char* Ximg = ws + 1048576;             // 8192 B
  float* mp = (float*)(ws + 1048576 + 8192);      // 16384 B
  float* v = (float*)(ws + 1048576 + 24576);      // 16384 B
  float* ck3 = (float*)(ws + 1048576 + 40960);    // 128 B

  prep1<<<32, 128, 0, stream>>>(means, P, w, mp, ck3);
  prep2<<<32, 128, 0, stream>>>(P, mp, v);
  prep3<<<2, 256, 0, stream>>>(v, Ximg);
  prep4<<<256, 256, 0, stream>>>(P, Aimg);
  gmm_main<<<NPTS / 128, 256, 0, stream>>>(x, Aimg, Ximg, ck3, out);
}